// Round 1
// baseline (356.000 us; speedup 1.0000x reference)
//
#include <hip/hip_runtime.h>
#include <climits>

// ---------------------------------------------------------------------------
// ChamferBoundarySDFLoss — bitwise-f32 replication of the numpy reference.
//
// Pipeline (all on `stream`, graph-capture safe):
//   memsetAsync: heads=-1, accumulators=0
//   k_count : per-chunk crossing counts (8 fields = {pred,gt} x B)
//   k_scan  : per-field exclusive prefix over chunk counts (+ totals)
//   k_emit  : ordered compaction of zero-crossing points (enumeration order
//             = z row-major, vertical (H-1)xW row-major, horizontal Hx(W-1))
//   k_chamfer: per pred-point: brute-force 1-NN over gt points (f32 sqrt,
//             strict-< first-min), bilinear pixel term, normal+dot, emit
//             4 scatter entries into per-pixel linked lists
//   k_gather: per pixel: fold entries in ascending entry-id (== numpy
//             np.add.at order) in f32, then fl(pred*dflat) -> f64 accum
//   k_final : means and combine -> f32 scalar
// ---------------------------------------------------------------------------

constexpr int B = 4, H = 768, W = 768, K = 4096;
constexpr int HW = H * W;
constexpr int NZ = H * W;          // 589824  z-candidates
constexpr int NV = (H - 1) * W;    // 589056  vertical candidates
constexpr int NH = H * (W - 1);    // 589056  horizontal candidates
constexpr int NTOT = NZ + NV + NH; // 1767936
constexpr int CHUNK = 16384;
constexpr int NCHUNK = (NTOT + CHUNK - 1) / CHUNK; // 108
constexpr int NFIELD = 2 * B;      // 8 (field f: sample f>>1, f&1: 0=pred 1=gt)

// workspace layout (bytes)
constexpr size_t OFF_INJ   = 0;                                   // double[B]
constexpr size_t OFF_PIX   = OFF_INJ + sizeof(double) * B;        // double[B]
constexpr size_t OFF_CNT   = OFF_PIX + sizeof(double) * B;        // int[NFIELD]
constexpr size_t OFF_CCNT  = OFF_CNT + sizeof(int) * NFIELD;      // int[NFIELD*NCHUNK]
constexpr size_t OFF_CBASE = OFF_CCNT + sizeof(int) * NFIELD * NCHUNK;
constexpr size_t OFF_PTS   = ((OFF_CBASE + sizeof(int) * NFIELD * NCHUNK) + 7) & ~size_t(7);
constexpr size_t OFF_HEADS = OFF_PTS + sizeof(float2) * NFIELD * K;
constexpr size_t OFF_NXT   = OFF_HEADS + sizeof(int) * (size_t)B * HW;
constexpr size_t OFF_EVAL  = OFF_NXT + sizeof(int) * (size_t)B * 4 * K;
constexpr size_t WS_NEED   = OFF_EVAL + sizeof(float) * (size_t)B * 4 * K; // ~10.2 MB

#define DEVFN __device__ __forceinline__

// Candidate g in [0,NTOT): predicate + (subpixel) point, bitwise == numpy.
DEVFN bool candidate(const float* __restrict__ sdf, int g, float& pr, float& pc) {
#pragma clang fp contract(off)
  if (g < NZ) {
    if (sdf[g] == 0.0f) {
      int r = g / W, c = g - r * W;
      pr = (float)r; pc = (float)c;
      return true;
    }
  } else if (g < NZ + NV) {
    int k = g - NZ;
    int r = k / W, c = k - r * W;
    float v1 = sdf[r * W + c], v2 = sdf[(r + 1) * W + c];
    if (v1 * v2 < 0.0f) {
      float a1 = fabsf(v1), a2 = fabsf(v2);
      float alpha = a1 / ((a1 + a2) + 1e-8f);   // |v1|/((|v1|+|v2|)+eps), left-assoc
      pr = (float)r + alpha;                    // fl(row + alpha)
      pc = (float)c;
      return true;
    }
  } else {
    int k = g - (NZ + NV);
    int r = k / (W - 1), c = k - r * (W - 1);
    float h1 = sdf[r * W + c], h2 = sdf[r * W + c + 1];
    if (h1 * h2 < 0.0f) {
      float a1 = fabsf(h1), a2 = fabsf(h2);
      float alpha = a1 / ((a1 + a2) + 1e-8f);
      pr = (float)r;
      pc = (float)c + alpha;
      return true;
    }
  }
  return false;
}

// central-difference gradient components (== compute_normals)
DEVFN float grad_r(const float* __restrict__ s, int r, int c) {
#pragma clang fp contract(off)
  if (r == 0)      return s[W + c] - s[c];
  if (r == H - 1)  return s[(H - 1) * W + c] - s[(H - 2) * W + c];
  return 0.5f * (s[(r + 1) * W + c] - s[(r - 1) * W + c]);
}
DEVFN float grad_c(const float* __restrict__ s, int r, int c) {
#pragma clang fp contract(off)
  if (c == 0)      return s[r * W + 1] - s[r * W];
  if (c == W - 1)  return s[r * W + W - 1] - s[r * W + W - 2];
  return 0.5f * (s[r * W + c + 1] - s[r * W + c - 1]);
}

DEVFN const float* field_sdf(const float* pred, const float* gt, int f) {
  return ((f & 1) ? gt : pred) + (size_t)(f >> 1) * HW;
}

__global__ __launch_bounds__(256) void k_count(const float* __restrict__ pred,
                                               const float* __restrict__ gt,
                                               int* __restrict__ chunk_count) {
  int blk = blockIdx.x;
  int f = blk / NCHUNK, ch = blk - f * NCHUNK;
  const float* sdf = field_sdf(pred, gt, f);
  int start = ch * CHUNK;
  int cnt = 0;
  float pr, pc;
  for (int t = threadIdx.x; t < CHUNK; t += 256) {
    int g = start + t;
    if (g < NTOT && candidate(sdf, g, pr, pc)) cnt++;
  }
  __shared__ int sc[256];
  sc[threadIdx.x] = cnt;
  __syncthreads();
  for (int s = 128; s > 0; s >>= 1) {
    if ((int)threadIdx.x < s) sc[threadIdx.x] += sc[threadIdx.x + s];
    __syncthreads();
  }
  if (threadIdx.x == 0) chunk_count[blk] = sc[0];
}

__global__ __launch_bounds__(256) void k_scan(const int* __restrict__ chunk_count,
                                              int* __restrict__ chunk_base,
                                              int* __restrict__ counts_raw) {
  __shared__ int s[NFIELD * NCHUNK];
  for (int t = threadIdx.x; t < NFIELD * NCHUNK; t += 256) s[t] = chunk_count[t];
  __syncthreads();
  if ((int)threadIdx.x < NFIELD) {
    int f = threadIdx.x;
    int acc = 0;
    for (int ch = 0; ch < NCHUNK; ++ch) {
      int v = s[f * NCHUNK + ch];
      chunk_base[f * NCHUNK + ch] = acc;
      acc += v;
    }
    counts_raw[f] = acc;
  }
}

__global__ __launch_bounds__(256) void k_emit(const float* __restrict__ pred,
                                              const float* __restrict__ gt,
                                              const int* __restrict__ chunk_base,
                                              float2* __restrict__ pts) {
  int blk = blockIdx.x;
  int f = blk / NCHUNK, ch = blk - f * NCHUNK;
  const float* sdf = field_sdf(pred, gt, f);
  int start = ch * CHUNK;
  int t0 = start + (int)threadIdx.x * 64;   // contiguous per-thread subrange keeps order
  float pr, pc;
  int myc = 0;
  for (int k = 0; k < 64; ++k) {
    int g = t0 + k;
    if (g < NTOT && candidate(sdf, g, pr, pc)) myc++;
  }
  __shared__ int sc[256];
  sc[threadIdx.x] = myc;
  __syncthreads();
  if (threadIdx.x == 0) {
    int a = 0;
    for (int t = 0; t < 256; ++t) { int v = sc[t]; sc[t] = a; a += v; }
  }
  __syncthreads();
  int pos = chunk_base[blk] + sc[threadIdx.x];
  float2* fp = pts + (size_t)f * K;
  for (int k = 0; k < 64; ++k) {
    int g = t0 + k;
    if (g < NTOT && candidate(sdf, g, pr, pc)) {
      if (pos < K) fp[pos] = make_float2(pr, pc);
      pos++;
    }
  }
}

__global__ __launch_bounds__(256) void k_chamfer(const float* __restrict__ pred,
                                                 const float2* __restrict__ pts,
                                                 const int* __restrict__ counts_raw,
                                                 int* __restrict__ heads,
                                                 int* __restrict__ nxt,
                                                 float* __restrict__ eval,
                                                 double* __restrict__ pix_acc) {
#pragma clang fp contract(off)
  int b = blockIdx.x >> 4;                       // 16 blocks x 256 = K threads/sample
  int i = ((blockIdx.x & 15) << 8) + threadIdx.x;
  const float* P = pred + (size_t)b * HW;
  int np_ = min(counts_raw[2 * b + 0], K);
  int ng  = min(counts_raw[2 * b + 1], K);
  const float2* pp = pts + (size_t)(2 * b + 0) * K;
  const float2* gp = pts + (size_t)(2 * b + 1) * K;
  bool active = (i < np_);
  float pr = 0.0f, pc = 0.0f;
  if (active) { float2 q = pp[i]; pr = q.x; pc = q.y; }

  float best = __builtin_inff();
  float bgr = 0.0f, bgc = 0.0f;
  __shared__ float2 tile[256];
  for (int t0 = 0; t0 < ng; t0 += 256) {
    int n = min(256, ng - t0);
    __syncthreads();
    if ((int)threadIdx.x < n) tile[threadIdx.x] = gp[t0 + threadIdx.x];
    __syncthreads();
    if (active) {
      for (int j = 0; j < n; ++j) {
        float dr = tile[j].x - pr;
        float dc = tile[j].y - pc;
        float d = sqrtf((dr * dr) + (dc * dc));   // no FMA, correctly-rounded sqrt
        if (d < best) { best = d; bgr = tile[j].x; bgc = tile[j].y; }  // first-min
      }
    }
  }
  if (!active) return;

  // _corner (floor -> int clip), ar/ac exact
  int r0 = (int)floorf(pr); r0 = r0 < 0 ? 0 : (r0 > H - 1 ? H - 1 : r0);
  int c0 = (int)floorf(pc); c0 = c0 < 0 ? 0 : (c0 > W - 1 ? W - 1 : c0);
  int r1 = (r0 + 1 > H - 1) ? H - 1 : r0 + 1;
  int c1 = (c0 + 1 > W - 1) ? W - 1 : c0 + 1;
  float ar = pr - (float)r0;
  float ac = pc - (float)c0;
  float omr = 1.0f - ar, omc = 1.0f - ac;
  float u00 = omr * omc, u01 = omr * ac, u10 = ar * omc, u11 = ar * ac;

  // pixel term: ((img*(1-ar))*(1-ac)) grouping, left-assoc sum (== bilinear_sample)
  float v00 = P[r0 * W + c0], v01 = P[r0 * W + c1];
  float v10 = P[r1 * W + c0], v11 = P[r1 * W + c1];
  float sval = (v00 * omr) * omc + (v01 * omr) * ac + (v10 * ar) * omc + (v11 * ar) * ac;
  atomicAdd(&pix_acc[b], (double)sval);

  // chamfer update (mask = min_dist<=3 & valid_p & any(valid_g); ng==0 -> best=inf)
  if (best <= 3.0f) {
    float grA = grad_r(P, r0, c0), grB = grad_r(P, r0, c1);
    float grC = grad_r(P, r1, c0), grD = grad_r(P, r1, c1);
    float gcA = grad_c(P, r0, c0), gcB = grad_c(P, r0, c1);
    float gcC = grad_c(P, r1, c0), gcD = grad_c(P, r1, c1);
    // weight-first grouping (== normals[..]*((1-ar)*(1-ac))), left-assoc sum
    float n_r = ((grA * u00 + grB * u01) + grC * u10) + grD * u11;
    float n_c = ((gcA * u00 + gcB * u01) + gcC * u10) + gcD * u11;
    float nn = sqrtf((n_r * n_r) + (n_c * n_c));
    float den = nn + 1e-8f;
    float nrm_r = n_r / den, nrm_c = n_c / den;
    float dr = bgr - pr, dc = bgc - pc;                 // dir_vec = gt - pred
    float dot = (dr * nrm_r) + (dc * nrm_c);
    dot = dot * 1.0f;                                   // UPDATE_SCALE
    if (dot != 0.0f) {
      int px[4] = { r0 * W + c0, r0 * W + c1, r1 * W + c0, r1 * W + c1 };
      float cv[4] = { dot * u00, dot * u01, dot * u10, dot * u11 };
      int base = b * 4 * K;
      for (int k2 = 0; k2 < 4; ++k2) {
        int e = k2 * K + i;                             // == numpy add.at order index
        eval[base + e] = cv[k2];
        nxt[base + e] = atomicExch(&heads[(size_t)b * HW + px[k2]], e);
      }
    }
  }
}

__global__ __launch_bounds__(256) void k_gather(const float* __restrict__ pred,
                                                const int* __restrict__ heads,
                                                const int* __restrict__ nxt,
                                                const float* __restrict__ eval,
                                                double* __restrict__ inj_acc) {
#pragma clang fp contract(off)
  int idx = blockIdx.x * 256 + threadIdx.x;
  if (idx >= B * HW) return;
  int h = heads[idx];
  if (h < 0) return;
  int b = idx / HW;
  int base = b * 4 * K;
  // fold this pixel's contributions in ascending entry-id == numpy's
  // sequential np.add.at order (corner-major, then point index), in f32.
  float acc = 0.0f;
  int last = -1;
  for (;;) {
    int bestE = INT_MAX;
    for (int e = h; e >= 0; e = nxt[base + e]) {
      if (e > last && e < bestE) bestE = e;
    }
    if (bestE == INT_MAX) break;
    acc = acc + eval[base + bestE];
    last = bestE;
  }
  float term = pred[idx] * acc;   // fl(pred * dflat)
  atomicAdd(&inj_acc[b], (double)term);
}

__global__ void k_final(const double* __restrict__ inj, const double* __restrict__ pix,
                        float* __restrict__ out) {
  if (threadIdx.x == 0 && blockIdx.x == 0) {
    double mi = (inj[0] + inj[1] + inj[2] + inj[3]) * 0.25;
    double mp = (pix[0] + pix[1] + pix[2] + pix[3]) * 0.25;
    out[0] = (float)(mi + mp);   // W_INJECT=W_PIXEL=1
  }
}

extern "C" void kernel_launch(void* const* d_in, const int* in_sizes, int n_in,
                              void* d_out, int out_size, void* d_ws, size_t ws_size,
                              hipStream_t stream) {
  const float* pred = (const float*)d_in[0];
  const float* gt   = (const float*)d_in[1];
  float* out = (float*)d_out;
  char* ws = (char*)d_ws;

  double* inj_acc    = (double*)(ws + OFF_INJ);
  double* pix_acc    = (double*)(ws + OFF_PIX);
  int*    counts_raw = (int*)(ws + OFF_CNT);
  int*    chunk_cnt  = (int*)(ws + OFF_CCNT);
  int*    chunk_base = (int*)(ws + OFF_CBASE);
  float2* pts        = (float2*)(ws + OFF_PTS);
  int*    heads      = (int*)(ws + OFF_HEADS);
  int*    nxt        = (int*)(ws + OFF_NXT);
  float*  eval       = (float*)(ws + OFF_EVAL);

  (void)in_sizes; (void)n_in; (void)out_size; (void)ws_size; // WS_NEED ~10.2MB

  hipMemsetAsync(ws + OFF_INJ, 0, sizeof(double) * 2 * B, stream);       // inj+pix = 0
  hipMemsetAsync(ws + OFF_HEADS, 0xFF, sizeof(int) * (size_t)B * HW, stream); // heads = -1

  k_count<<<dim3(NFIELD * NCHUNK), dim3(256), 0, stream>>>(pred, gt, chunk_cnt);
  k_scan<<<dim3(1), dim3(256), 0, stream>>>(chunk_cnt, chunk_base, counts_raw);
  k_emit<<<dim3(NFIELD * NCHUNK), dim3(256), 0, stream>>>(pred, gt, chunk_base, pts);
  k_chamfer<<<dim3(B * (K / 256)), dim3(256), 0, stream>>>(pred, pts, counts_raw,
                                                           heads, nxt, eval, pix_acc);
  k_gather<<<dim3((B * HW + 255) / 256), dim3(256), 0, stream>>>(pred, heads, nxt,
                                                                 eval, inj_acc);
  k_final<<<dim3(1), dim3(1), 0, stream>>>(inj_acc, pix_acc, out);
}

// Round 2
// 146.339 us; speedup vs baseline: 2.4327x; 2.4327x over previous
//
#include <hip/hip_runtime.h>
#include <climits>

// ---------------------------------------------------------------------------
// ChamferBoundarySDFLoss — bitwise-f32 replication of the numpy reference.
// R2: coalesced ballot-based compaction (masks cached), 8-way-split NN with
// packed atomicMin key, block-reduced f64 accumulations.
// ---------------------------------------------------------------------------

constexpr int B = 4, H = 768, W = 768, K = 4096;
constexpr int HW = H * W;
constexpr int NZ = H * W;          // 589824  z-candidates
constexpr int NV = (H - 1) * W;    // 589056  vertical candidates
constexpr int NH = H * (W - 1);    // 589056  horizontal candidates
constexpr int NTOT = NZ + NV + NH; // 1767936
constexpr int WCH = 4096;                      // elements per wave-chunk
constexpr int NWCH = (NTOT + WCH - 1) / WCH;   // 432 (exact: 431.625 -> 432)
constexpr int CBLK = NWCH / 4;                 // 108 blocks/field (4 waves each)
constexpr int NFIELD = 2 * B;                  // 8 (f>>1 = sample, f&1: 0=pred 1=gt)
constexpr int GSPLIT = 8;                      // gt-range split for NN
constexpr int GRNG = K / GSPLIT;               // 512 gt pts per NN block

// workspace layout (bytes)
constexpr size_t OFF_INJ   = 0;                                        // double[B]
constexpr size_t OFF_PIX   = OFF_INJ + sizeof(double) * B;             // double[B]
constexpr size_t OFF_CNT   = OFF_PIX + sizeof(double) * B;             // int[NFIELD]
constexpr size_t OFF_WCNT  = OFF_CNT + sizeof(int) * NFIELD;           // int[NFIELD*NWCH]
constexpr size_t OFF_WBASE = OFF_WCNT + sizeof(int) * NFIELD * NWCH;   // int[NFIELD*NWCH]
constexpr size_t OFF_MASKS = (OFF_WBASE + sizeof(int) * NFIELD * NWCH + 7) & ~size_t(7);
constexpr size_t OFF_PTS   = OFF_MASKS + sizeof(unsigned long long) * NFIELD * NWCH * 64;
constexpr size_t OFF_NNKEY = OFF_PTS + sizeof(float2) * NFIELD * K;    // ull[B*K]
constexpr size_t OFF_HEADS = OFF_NNKEY + sizeof(unsigned long long) * (size_t)B * K;
constexpr size_t OFF_NXT   = OFF_HEADS + sizeof(int) * (size_t)B * HW;
constexpr size_t OFF_EVAL  = OFF_NXT + sizeof(int) * (size_t)B * 4 * K;
constexpr size_t WS_NEED   = OFF_EVAL + sizeof(float) * (size_t)B * 4 * K; // ~12.0 MB

#define DEVFN __device__ __forceinline__

// predicate only (count pass): no alpha computation
DEVFN bool predicate(const float* __restrict__ s, int g) {
  if (g < NZ) return s[g] == 0.0f;
  if (g < NZ + NV) { int k = g - NZ; return s[k] * s[k + W] < 0.0f; }
  int k = g - (NZ + NV);
  int r = k / (W - 1), c = k - r * (W - 1);
  return s[r * W + c] * s[r * W + c + 1] < 0.0f;
}

// full candidate point, bitwise == numpy
DEVFN void candidate_pt(const float* __restrict__ s, int g, float& pr, float& pc) {
#pragma clang fp contract(off)
  if (g < NZ) {
    int r = g / W, c = g - r * W;
    pr = (float)r; pc = (float)c;
  } else if (g < NZ + NV) {
    int k = g - NZ;
    int r = k / W, c = k - r * W;
    float v1 = s[r * W + c], v2 = s[(r + 1) * W + c];
    float a1 = fabsf(v1), a2 = fabsf(v2);
    float alpha = a1 / ((a1 + a2) + 1e-8f);     // left-assoc, eps outside
    pr = (float)r + alpha;
    pc = (float)c;
  } else {
    int k = g - (NZ + NV);
    int r = k / (W - 1), c = k - r * (W - 1);
    float h1 = s[r * W + c], h2 = s[r * W + c + 1];
    float a1 = fabsf(h1), a2 = fabsf(h2);
    float alpha = a1 / ((a1 + a2) + 1e-8f);
    pr = (float)r;
    pc = (float)c + alpha;
  }
}

DEVFN float grad_r(const float* __restrict__ s, int r, int c) {
#pragma clang fp contract(off)
  if (r == 0)      return s[W + c] - s[c];
  if (r == H - 1)  return s[(H - 1) * W + c] - s[(H - 2) * W + c];
  return 0.5f * (s[(r + 1) * W + c] - s[(r - 1) * W + c]);
}
DEVFN float grad_c(const float* __restrict__ s, int r, int c) {
#pragma clang fp contract(off)
  if (c == 0)      return s[r * W + 1] - s[r * W];
  if (c == W - 1)  return s[r * W + W - 1] - s[r * W + W - 2];
  return 0.5f * (s[r * W + c + 1] - s[r * W + c - 1]);
}

DEVFN const float* field_sdf(const float* pred, const float* gt, int f) {
  return ((f & 1) ? gt : pred) + (size_t)(f >> 1) * HW;
}

// count pass: coalesced ballot, store masks + per-chunk counts
__global__ __launch_bounds__(256) void k_count(const float* __restrict__ pred,
                                               const float* __restrict__ gt,
                                               unsigned long long* __restrict__ masks,
                                               int* __restrict__ wave_cnt) {
  int f = blockIdx.x / CBLK, cb = blockIdx.x - f * CBLK;
  int wave = threadIdx.x >> 6, lane = threadIdx.x & 63;
  int ch = cb * 4 + wave;                       // 432 = 108*4 exact
  const float* sdf = field_sdf(pred, gt, f);
  int start = ch * WCH;
  unsigned long long* mrow = masks + ((size_t)f * NWCH + ch) * 64;
  int cnt = 0;
  for (int it = 0; it < 64; ++it) {
    int g = start + it * 64 + lane;
    bool p = (g < NTOT) && predicate(sdf, g);
    unsigned long long m = __ballot(p);
    if (lane == 0) mrow[it] = m;
    cnt += __popcll(m);
  }
  if (lane == 0) wave_cnt[f * NWCH + ch] = cnt;
}

// per-field exclusive scan over chunk counts (wave-parallel, shfl)
__global__ __launch_bounds__(512) void k_scan(const int* __restrict__ wave_cnt,
                                              int* __restrict__ wave_base,
                                              int* __restrict__ counts_raw) {
  int f = threadIdx.x >> 6, lane = threadIdx.x & 63;   // 8 waves = 8 fields
  int running = 0;
  for (int base = 0; base < NWCH; base += 64) {
    int idx = base + lane;
    int v = (idx < NWCH) ? wave_cnt[f * NWCH + idx] : 0;
    int incl = v;
    for (int off = 1; off < 64; off <<= 1) {
      int n = __shfl_up(incl, off, 64);
      if (lane >= off) incl += n;
    }
    if (idx < NWCH) wave_base[f * NWCH + idx] = running + (incl - v);
    running += __shfl(incl, 63, 64);
  }
  if (lane == 0) counts_raw[f] = running;
}

// mask-driven ordered emit: only real crossings touch the sdf
__global__ __launch_bounds__(256) void k_emit(const float* __restrict__ pred,
                                              const float* __restrict__ gt,
                                              const unsigned long long* __restrict__ masks,
                                              const int* __restrict__ wave_base,
                                              float2* __restrict__ pts) {
  int f = blockIdx.x / CBLK, cb = blockIdx.x - f * CBLK;
  int wave = threadIdx.x >> 6, lane = threadIdx.x & 63;
  int ch = cb * 4 + wave;
  const float* sdf = field_sdf(pred, gt, f);
  int start = ch * WCH;
  const unsigned long long* mrow = masks + ((size_t)f * NWCH + ch) * 64;
  float2* fp = pts + (size_t)f * K;
  int base = wave_base[f * NWCH + ch];
  for (int it = 0; it < 64 && base < K; ++it) {
    unsigned long long m = mrow[it];
    if (m == 0ull) continue;
    if ((m >> lane) & 1ull) {
      float pr, pc;
      candidate_pt(sdf, start + it * 64 + lane, pr, pc);
      int pos = base + __popcll(m & ((1ull << lane) - 1ull));
      if (pos < K) fp[pos] = make_float2(pr, pc);
    }
    base += __popcll(m);
  }
}

// 1-NN, gt dimension split GSPLIT ways; order-exact via packed (distbits, j) key
__global__ __launch_bounds__(256) void k_nn(const float2* __restrict__ pts,
                                            const int* __restrict__ counts_raw,
                                            unsigned long long* __restrict__ nnkey) {
#pragma clang fp contract(off)
  int b = blockIdx.x / (16 * GSPLIT);
  int rem = blockIdx.x - b * (16 * GSPLIT);
  int ib = rem / GSPLIT, ig = rem - ib * GSPLIT;
  int np_ = min(counts_raw[2 * b + 0], K);
  int ng  = min(counts_raw[2 * b + 1], K);
  int j0 = ig * GRNG, j1 = min(j0 + GRNG, ng);
  if (j0 >= j1) return;                         // uniform over block
  const float2* gp = pts + (size_t)(2 * b + 1) * K;
  __shared__ float2 tile[GRNG];
  for (int t = threadIdx.x; t < j1 - j0; t += 256) tile[t] = gp[j0 + t];
  __syncthreads();
  int i = ib * 256 + (int)threadIdx.x;
  if (i >= np_) return;
  float2 q = pts[(size_t)(2 * b) * K + i];
  float pr = q.x, pc = q.y;
  float best = __builtin_inff();
  int bj = -1;
  int nj = j1 - j0;
  for (int j = 0; j < nj; ++j) {
    float dr = tile[j].x - pr;
    float dc = tile[j].y - pc;
    float d = sqrtf((dr * dr) + (dc * dc));     // no FMA, CR sqrt
    if (d < best) { best = d; bj = j0 + j; }    // strict < = first-min
  }
  unsigned long long key =
      ((unsigned long long)__float_as_uint(best) << 32) | (unsigned)bj;
  atomicMin(&nnkey[(size_t)b * K + i], key);    // ties -> min j (numpy argmin)
}

// pixel term + chamfer scatter
__global__ __launch_bounds__(256) void k_post(const float* __restrict__ pred,
                                              const float2* __restrict__ pts,
                                              const int* __restrict__ counts_raw,
                                              const unsigned long long* __restrict__ nnkey,
                                              int* __restrict__ heads,
                                              int* __restrict__ nxt,
                                              float* __restrict__ eval,
                                              double* __restrict__ pix_acc) {
#pragma clang fp contract(off)
  int b = blockIdx.x >> 4;
  int i = ((blockIdx.x & 15) << 8) + (int)threadIdx.x;
  const float* P = pred + (size_t)b * HW;
  int np_ = min(counts_raw[2 * b + 0], K);
  bool active = (i < np_);
  float sval = 0.0f;
  if (active) {
    float2 q = pts[(size_t)(2 * b) * K + i];
    float pr = q.x, pc = q.y;

    int r0 = (int)floorf(pr); r0 = r0 < 0 ? 0 : (r0 > H - 1 ? H - 1 : r0);
    int c0 = (int)floorf(pc); c0 = c0 < 0 ? 0 : (c0 > W - 1 ? W - 1 : c0);
    int r1 = (r0 + 1 > H - 1) ? H - 1 : r0 + 1;
    int c1 = (c0 + 1 > W - 1) ? W - 1 : c0 + 1;
    float ar = pr - (float)r0;
    float ac = pc - (float)c0;
    float omr = 1.0f - ar, omc = 1.0f - ac;
    float u00 = omr * omc, u01 = omr * ac, u10 = ar * omc, u11 = ar * ac;

    // pixel term: ((img*(1-ar))*(1-ac)) grouping, left-assoc (== bilinear_sample)
    float v00 = P[r0 * W + c0], v01 = P[r0 * W + c1];
    float v10 = P[r1 * W + c0], v11 = P[r1 * W + c1];
    sval = (v00 * omr) * omc + (v01 * omr) * ac + (v10 * ar) * omc + (v11 * ar) * ac;

    unsigned long long key = nnkey[(size_t)b * K + i];
    float best = __uint_as_float((unsigned)(key >> 32));   // all-ones -> NaN -> false
    if (best <= 3.0f) {
      const float2* gp = pts + (size_t)(2 * b + 1) * K;
      float2 g = gp[(unsigned)(key & 0xffffffffu)];
      float grA = grad_r(P, r0, c0), grB = grad_r(P, r0, c1);
      float grC = grad_r(P, r1, c0), grD = grad_r(P, r1, c1);
      float gcA = grad_c(P, r0, c0), gcB = grad_c(P, r0, c1);
      float gcC = grad_c(P, r1, c0), gcD = grad_c(P, r1, c1);
      float n_r = ((grA * u00 + grB * u01) + grC * u10) + grD * u11;
      float n_c = ((gcA * u00 + gcB * u01) + gcC * u10) + gcD * u11;
      float nn = sqrtf((n_r * n_r) + (n_c * n_c));
      float den = nn + 1e-8f;
      float nrm_r = n_r / den, nrm_c = n_c / den;
      float dr = g.x - pr, dc = g.y - pc;                  // dir_vec = gt - pred
      float dot = (dr * nrm_r) + (dc * nrm_c);
      dot = dot * 1.0f;                                    // UPDATE_SCALE
      if (dot != 0.0f) {
        int px[4] = { r0 * W + c0, r0 * W + c1, r1 * W + c0, r1 * W + c1 };
        float cv[4] = { dot * u00, dot * u01, dot * u10, dot * u11 };
        int basee = b * 4 * K;
        for (int k2 = 0; k2 < 4; ++k2) {
          int e = k2 * K + i;                              // numpy add.at order id
          eval[basee + e] = cv[k2];
          nxt[basee + e] = atomicExch(&heads[(size_t)b * HW + px[k2]], e);
        }
      }
    }
  }
  // block-reduce pixel sum (f64; reassociation noise ~1e-19, irrelevant)
  __shared__ double red[256];
  red[threadIdx.x] = (double)sval;
  __syncthreads();
  for (int s = 128; s > 0; s >>= 1) {
    if ((int)threadIdx.x < s) red[threadIdx.x] += red[threadIdx.x + s];
    __syncthreads();
  }
  if (threadIdx.x == 0 && red[0] != 0.0) atomicAdd(&pix_acc[b], red[0]);
}

__global__ __launch_bounds__(256) void k_gather(const float* __restrict__ pred,
                                                const int* __restrict__ heads,
                                                const int* __restrict__ nxt,
                                                const float* __restrict__ eval,
                                                double* __restrict__ inj_acc) {
#pragma clang fp contract(off)
  int idx = blockIdx.x * 256 + (int)threadIdx.x;
  int b = idx / HW;
  float term = 0.0f;
  int h = (idx < B * HW) ? heads[idx] : -1;
  if (h >= 0) {
    int base = b * 4 * K;
    // fold entries ascending by id == numpy sequential np.add.at order, in f32
    float acc = 0.0f;
    int last = -1;
    for (;;) {
      int bestE = INT_MAX;
      for (int e = h; e >= 0; e = nxt[base + e])
        if (e > last && e < bestE) bestE = e;
      if (bestE == INT_MAX) break;
      acc = acc + eval[base + bestE];
      last = bestE;
    }
    term = pred[idx] * acc;                     // fl(pred * dflat)
  }
  __shared__ double red[256];
  red[threadIdx.x] = (double)term;
  __syncthreads();
  for (int s = 128; s > 0; s >>= 1) {
    if ((int)threadIdx.x < s) red[threadIdx.x] += red[threadIdx.x + s];
    __syncthreads();
  }
  if (threadIdx.x == 0 && red[0] != 0.0 && idx < B * HW)
    atomicAdd(&inj_acc[blockIdx.x * 256 / HW], red[0]);   // block never spans samples (HW%256==0)
}

__global__ void k_final(const double* __restrict__ inj, const double* __restrict__ pix,
                        float* __restrict__ out) {
  if (threadIdx.x == 0 && blockIdx.x == 0) {
    double mi = (inj[0] + inj[1] + inj[2] + inj[3]) * 0.25;
    double mp = (pix[0] + pix[1] + pix[2] + pix[3]) * 0.25;
    out[0] = (float)(mi + mp);   // W_INJECT = W_PIXEL = 1
  }
}

extern "C" void kernel_launch(void* const* d_in, const int* in_sizes, int n_in,
                              void* d_out, int out_size, void* d_ws, size_t ws_size,
                              hipStream_t stream) {
  const float* pred = (const float*)d_in[0];
  const float* gt   = (const float*)d_in[1];
  float* out = (float*)d_out;
  char* ws = (char*)d_ws;

  double* inj_acc    = (double*)(ws + OFF_INJ);
  double* pix_acc    = (double*)(ws + OFF_PIX);
  int*    counts_raw = (int*)(ws + OFF_CNT);
  int*    wave_cnt   = (int*)(ws + OFF_WCNT);
  int*    wave_base  = (int*)(ws + OFF_WBASE);
  unsigned long long* masks = (unsigned long long*)(ws + OFF_MASKS);
  float2* pts        = (float2*)(ws + OFF_PTS);
  unsigned long long* nnkey = (unsigned long long*)(ws + OFF_NNKEY);
  int*    heads      = (int*)(ws + OFF_HEADS);
  int*    nxt        = (int*)(ws + OFF_NXT);
  float*  eval       = (float*)(ws + OFF_EVAL);

  (void)in_sizes; (void)n_in; (void)out_size; (void)ws_size; // WS_NEED ~12.0 MB

  hipMemsetAsync(ws + OFF_INJ, 0, sizeof(double) * 2 * B, stream);
  hipMemsetAsync(nnkey, 0xFF, sizeof(unsigned long long) * (size_t)B * K, stream);
  hipMemsetAsync(heads, 0xFF, sizeof(int) * (size_t)B * HW, stream);

  k_count<<<dim3(NFIELD * CBLK), dim3(256), 0, stream>>>(pred, gt, masks, wave_cnt);
  k_scan<<<dim3(1), dim3(512), 0, stream>>>(wave_cnt, wave_base, counts_raw);
  k_emit<<<dim3(NFIELD * CBLK), dim3(256), 0, stream>>>(pred, gt, masks, wave_base, pts);
  k_nn<<<dim3(B * 16 * GSPLIT), dim3(256), 0, stream>>>(pts, counts_raw, nnkey);
  k_post<<<dim3(B * 16), dim3(256), 0, stream>>>(pred, pts, counts_raw, nnkey,
                                                 heads, nxt, eval, pix_acc);
  k_gather<<<dim3(B * HW / 256), dim3(256), 0, stream>>>(pred, heads, nxt, eval, inj_acc);
  k_final<<<dim3(1), dim3(1), 0, stream>>>(inj_acc, pix_acc, out);
}

// Round 3
// 112.498 us; speedup vs baseline: 3.1645x; 1.3008x over previous
//
#include <hip/hip_runtime.h>
#include <climits>

// ---------------------------------------------------------------------------
// ChamferBoundarySDFLoss — bitwise-f32 replication of the numpy reference.
// R3: pruned NN (conservative sq-dist test, exact path for survivors),
// per-split NN partials (no atomics/memset), scan folded into emit,
// head-clear folded into count. 6 dispatches total.
// ---------------------------------------------------------------------------

constexpr int B = 4, H = 768, W = 768, K = 4096;
constexpr int HW = H * W;
constexpr int NZ = H * W;          // 589824  z-candidates
constexpr int NV = (H - 1) * W;    // 589056  vertical candidates
constexpr int NH = H * (W - 1);    // 589056  horizontal candidates
constexpr int NTOT = NZ + NV + NH; // 1767936
constexpr int WCH = 4096;                      // elements per wave-chunk
constexpr int NWCH = (NTOT + WCH - 1) / WCH;   // 432
constexpr int CBLK = NWCH / 4;                 // 108 blocks/field (4 waves each)
constexpr int NFIELD = 2 * B;                  // 8 (f>>1 = sample, f&1: 0=pred 1=gt)
constexpr int GSPLIT = 16;                     // gt-range split for NN
constexpr int GRNG = K / GSPLIT;               // 256 gt pts per NN block

// workspace layout (bytes)
constexpr size_t OFF_ACC   = 0;                                       // double[8]: inj[4], pix[4]
constexpr size_t OFF_CNT   = OFF_ACC + sizeof(double) * 8;            // int[NFIELD]
constexpr size_t OFF_WCNT  = OFF_CNT + sizeof(int) * NFIELD;          // int[NFIELD*NWCH]
constexpr size_t OFF_MASKS = (OFF_WCNT + sizeof(int) * NFIELD * NWCH + 7) & ~size_t(7);
constexpr size_t OFF_PTS   = OFF_MASKS + sizeof(unsigned long long) * NFIELD * NWCH * 64;
constexpr size_t OFF_PART  = OFF_PTS + sizeof(float2) * NFIELD * K;   // ull[B*GSPLIT*K]
constexpr size_t OFF_HEADS = OFF_PART + sizeof(unsigned long long) * (size_t)B * GSPLIT * K;
constexpr size_t OFF_NXT   = OFF_HEADS + sizeof(int) * (size_t)B * HW;
constexpr size_t OFF_EVAL  = OFF_NXT + sizeof(int) * (size_t)B * 4 * K;
constexpr size_t WS_NEED   = OFF_EVAL + sizeof(float) * (size_t)B * 4 * K; // ~14.1 MB

#define DEVFN __device__ __forceinline__

// predicate only (count pass): no alpha computation
DEVFN bool predicate(const float* __restrict__ s, int g) {
  if (g < NZ) return s[g] == 0.0f;
  if (g < NZ + NV) { int k = g - NZ; return s[k] * s[k + W] < 0.0f; }
  int k = g - (NZ + NV);
  int r = k / (W - 1), c = k - r * (W - 1);
  return s[r * W + c] * s[r * W + c + 1] < 0.0f;
}

// full candidate point, bitwise == numpy
DEVFN void candidate_pt(const float* __restrict__ s, int g, float& pr, float& pc) {
#pragma clang fp contract(off)
  if (g < NZ) {
    int r = g / W, c = g - r * W;
    pr = (float)r; pc = (float)c;
  } else if (g < NZ + NV) {
    int k = g - NZ;
    int r = k / W, c = k - r * W;
    float v1 = s[r * W + c], v2 = s[(r + 1) * W + c];
    float a1 = fabsf(v1), a2 = fabsf(v2);
    float alpha = a1 / ((a1 + a2) + 1e-8f);     // left-assoc, eps outside
    pr = (float)r + alpha;
    pc = (float)c;
  } else {
    int k = g - (NZ + NV);
    int r = k / (W - 1), c = k - r * (W - 1);
    float h1 = s[r * W + c], h2 = s[r * W + c + 1];
    float a1 = fabsf(h1), a2 = fabsf(h2);
    float alpha = a1 / ((a1 + a2) + 1e-8f);
    pr = (float)r;
    pc = (float)c + alpha;
  }
}

DEVFN float grad_r(const float* __restrict__ s, int r, int c) {
#pragma clang fp contract(off)
  if (r == 0)      return s[W + c] - s[c];
  if (r == H - 1)  return s[(H - 1) * W + c] - s[(H - 2) * W + c];
  return 0.5f * (s[(r + 1) * W + c] - s[(r - 1) * W + c]);
}
DEVFN float grad_c(const float* __restrict__ s, int r, int c) {
#pragma clang fp contract(off)
  if (c == 0)      return s[r * W + 1] - s[r * W];
  if (c == W - 1)  return s[r * W + W - 1] - s[r * W + W - 2];
  return 0.5f * (s[r * W + c + 1] - s[r * W + c - 1]);
}

DEVFN const float* field_sdf(const float* pred, const float* gt, int f) {
  return ((f & 1) ? gt : pred) + (size_t)(f >> 1) * HW;
}

// count pass: coalesced ballot -> masks + per-chunk counts. Also clears
// heads (-1) and the 8 f64 accumulators (grid-stride; used only by later
// kernels in the same stream).
__global__ __launch_bounds__(256) void k_count(const float* __restrict__ pred,
                                               const float* __restrict__ gt,
                                               unsigned long long* __restrict__ masks,
                                               int* __restrict__ wave_cnt,
                                               int* __restrict__ heads,
                                               double* __restrict__ acc) {
  // fold-in clears
  for (int idx = blockIdx.x * 256 + (int)threadIdx.x; idx < B * HW;
       idx += gridDim.x * 256)
    heads[idx] = -1;
  if (blockIdx.x == 0 && threadIdx.x < 8) acc[threadIdx.x] = 0.0;

  int f = blockIdx.x / CBLK, cb = blockIdx.x - f * CBLK;
  int wave = threadIdx.x >> 6, lane = threadIdx.x & 63;
  int ch = cb * 4 + wave;
  const float* sdf = field_sdf(pred, gt, f);
  int start = ch * WCH;
  unsigned long long* mrow = masks + ((size_t)f * NWCH + ch) * 64;
  int cnt = 0;
  for (int it = 0; it < 64; ++it) {
    int g = start + it * 64 + lane;
    bool p = (g < NTOT) && predicate(sdf, g);
    unsigned long long m = __ballot(p);
    if (lane == 0) mrow[it] = m;
    cnt += __popcll(m);
  }
  if (lane == 0) wave_cnt[f * NWCH + ch] = cnt;
}

// mask-driven ordered emit with inline per-block prefix over chunk counts
__global__ __launch_bounds__(256) void k_emit(const float* __restrict__ pred,
                                              const float* __restrict__ gt,
                                              const unsigned long long* __restrict__ masks,
                                              const int* __restrict__ wave_cnt,
                                              float2* __restrict__ pts,
                                              int* __restrict__ counts_raw) {
  int f = blockIdx.x / CBLK, cb = blockIdx.x - f * CBLK;
  __shared__ int cnt_s[NWCH];
  for (int t = threadIdx.x; t < NWCH; t += 256) cnt_s[t] = wave_cnt[f * NWCH + t];
  __syncthreads();
  int wave = threadIdx.x >> 6, lane = threadIdx.x & 63;
  int ch = cb * 4 + wave;
  // exclusive prefix: sum of all chunks before ch
  int a = 0;
  for (int idx = lane; idx < ch; idx += 64) a += cnt_s[idx];
  for (int off = 32; off > 0; off >>= 1) a += __shfl_xor(a, off, 64);
  int base = a;
  // field total (block 0, wave 0)
  if (cb == 0 && wave == 0) {
    int t2 = 0;
    for (int idx = lane; idx < NWCH; idx += 64) t2 += cnt_s[idx];
    for (int off = 32; off > 0; off >>= 1) t2 += __shfl_xor(t2, off, 64);
    if (lane == 0) counts_raw[f] = t2;
  }
  const float* sdf = field_sdf(pred, gt, f);
  int start = ch * WCH;
  const unsigned long long* mrow = masks + ((size_t)f * NWCH + ch) * 64;
  float2* fp = pts + (size_t)f * K;
  for (int it = 0; it < 64 && base < K; ++it) {
    unsigned long long m = mrow[it];
    if (m == 0ull) continue;
    if ((m >> lane) & 1ull) {
      float pr, pc;
      candidate_pt(sdf, start + it * 64 + lane, pr, pc);
      int pos = base + __popcll(m & ((1ull << lane) - 1ull));
      if (pos < K) fp[pos] = make_float2(pr, pc);
    }
    base += __popcll(m);
  }
}

// 1-NN over a gt sub-range, pruned by conservative squared distance.
// Survivors (sq <= 9.0001; exact admissible max ~9.0000007) recompute the
// bitwise-exact d = sqrtf((dr*dr)+(dc*dc)); strict < keeps first-min.
// Partial key (distbits<<32)|j written unconditionally -> no memset/atomics.
__global__ __launch_bounds__(256) void k_nn(const float2* __restrict__ pts,
                                            const int* __restrict__ counts_raw,
                                            unsigned long long* __restrict__ part) {
#pragma clang fp contract(off)
  int b = blockIdx.x / (16 * GSPLIT);
  int rem = blockIdx.x - b * (16 * GSPLIT);
  int ib = rem / GSPLIT, ig = rem - ib * GSPLIT;
  int np_ = min(counts_raw[2 * b + 0], K);
  int ng  = min(counts_raw[2 * b + 1], K);
  int j0 = ig * GRNG, j1 = min(j0 + GRNG, ng);
  int n = j1 - j0;                               // may be <= 0
  const float2* gp = pts + (size_t)(2 * b + 1) * K;
  __shared__ float2 tile[GRNG];
  for (int t = threadIdx.x; t < n; t += 256) tile[t] = gp[j0 + t];
  __syncthreads();
  int i = ib * 256 + (int)threadIdx.x;
  bool active = (i < np_);
  float best = __builtin_inff();
  unsigned bj = 0xffffffffu;
  if (active) {
    float2 q = pts[(size_t)(2 * b) * K + i];
    float pr = q.x, pc = q.y;
#pragma unroll 4
    for (int j = 0; j < n; ++j) {
      float dr = tile[j].x - pr;
      float dc = tile[j].y - pc;
      float sqf = fmaf(dr, dr, dc * dc);         // prune value (fma ok: slack 1e-5)
      if (sqf <= 9.0001f) {
        float d = sqrtf((dr * dr) + (dc * dc));  // exact: no contraction, CR sqrt
        if (d < best) { best = d; bj = (unsigned)(j0 + j); }
      }
    }
  }
  unsigned long long key = active
      ? (((unsigned long long)__float_as_uint(best) << 32) | bj)
      : ~0ull;
  part[((size_t)b * GSPLIT + ig) * K + i] = key;
}

// pixel term + chamfer scatter; min-reduces the GSPLIT partial keys
__global__ __launch_bounds__(256) void k_post(const float* __restrict__ pred,
                                              const float2* __restrict__ pts,
                                              const int* __restrict__ counts_raw,
                                              const unsigned long long* __restrict__ part,
                                              int* __restrict__ heads,
                                              int* __restrict__ nxt,
                                              float* __restrict__ eval,
                                              double* __restrict__ acc) {
#pragma clang fp contract(off)
  int b = blockIdx.x >> 4;
  int i = ((blockIdx.x & 15) << 8) + (int)threadIdx.x;
  const float* P = pred + (size_t)b * HW;
  int np_ = min(counts_raw[2 * b + 0], K);
  bool active = (i < np_);
  float sval = 0.0f;
  if (active) {
    // min over split partials (ascending split = ascending j; packed-key min
    // => dist tie -> min j == numpy first-occurrence argmin)
    unsigned long long key = ~0ull;
    for (int s = 0; s < GSPLIT; ++s) {
      unsigned long long k2 = part[((size_t)b * GSPLIT + s) * K + i];
      key = k2 < key ? k2 : key;
    }
    float2 q = pts[(size_t)(2 * b) * K + i];
    float pr = q.x, pc = q.y;

    int r0 = (int)floorf(pr); r0 = r0 < 0 ? 0 : (r0 > H - 1 ? H - 1 : r0);
    int c0 = (int)floorf(pc); c0 = c0 < 0 ? 0 : (c0 > W - 1 ? W - 1 : c0);
    int r1 = (r0 + 1 > H - 1) ? H - 1 : r0 + 1;
    int c1 = (c0 + 1 > W - 1) ? W - 1 : c0 + 1;
    float ar = pr - (float)r0;
    float ac = pc - (float)c0;
    float omr = 1.0f - ar, omc = 1.0f - ac;
    float u00 = omr * omc, u01 = omr * ac, u10 = ar * omc, u11 = ar * ac;

    // pixel term: ((img*(1-ar))*(1-ac)) grouping, left-assoc (== bilinear_sample)
    float v00 = P[r0 * W + c0], v01 = P[r0 * W + c1];
    float v10 = P[r1 * W + c0], v11 = P[r1 * W + c1];
    sval = (v00 * omr) * omc + (v01 * omr) * ac + (v10 * ar) * omc + (v11 * ar) * ac;

    float best = __uint_as_float((unsigned)(key >> 32));   // ~0 -> NaN -> false
    if (best <= 3.0f) {
      const float2* gp = pts + (size_t)(2 * b + 1) * K;
      float2 g = gp[(unsigned)(key & 0xffffffffu)];
      float grA = grad_r(P, r0, c0), grB = grad_r(P, r0, c1);
      float grC = grad_r(P, r1, c0), grD = grad_r(P, r1, c1);
      float gcA = grad_c(P, r0, c0), gcB = grad_c(P, r0, c1);
      float gcC = grad_c(P, r1, c0), gcD = grad_c(P, r1, c1);
      float n_r = ((grA * u00 + grB * u01) + grC * u10) + grD * u11;
      float n_c = ((gcA * u00 + gcB * u01) + gcC * u10) + gcD * u11;
      float nn = sqrtf((n_r * n_r) + (n_c * n_c));
      float den = nn + 1e-8f;
      float nrm_r = n_r / den, nrm_c = n_c / den;
      float dr = g.x - pr, dc = g.y - pc;                  // dir_vec = gt - pred
      float dot = (dr * nrm_r) + (dc * nrm_c);
      dot = dot * 1.0f;                                    // UPDATE_SCALE
      if (dot != 0.0f) {
        int px[4] = { r0 * W + c0, r0 * W + c1, r1 * W + c0, r1 * W + c1 };
        float cv[4] = { dot * u00, dot * u01, dot * u10, dot * u11 };
        int basee = b * 4 * K;
        for (int k2 = 0; k2 < 4; ++k2) {
          int e = k2 * K + i;                              // numpy add.at order id
          eval[basee + e] = cv[k2];
          nxt[basee + e] = atomicExch(&heads[(size_t)b * HW + px[k2]], e);
        }
      }
    }
  }
  // block-reduce pixel sum (f64)
  __shared__ double red[256];
  red[threadIdx.x] = (double)sval;
  __syncthreads();
  for (int s = 128; s > 0; s >>= 1) {
    if ((int)threadIdx.x < s) red[threadIdx.x] += red[threadIdx.x + s];
    __syncthreads();
  }
  if (threadIdx.x == 0 && red[0] != 0.0) atomicAdd(&acc[4 + b], red[0]);
}

__global__ __launch_bounds__(256) void k_gather(const float* __restrict__ pred,
                                                const int* __restrict__ heads,
                                                const int* __restrict__ nxt,
                                                const float* __restrict__ eval,
                                                double* __restrict__ acc) {
#pragma clang fp contract(off)
  int idx = blockIdx.x * 256 + (int)threadIdx.x;
  int b = idx / HW;
  float term = 0.0f;
  int h = heads[idx];
  if (h >= 0) {
    int base = b * 4 * K;
    // fold entries ascending by id == numpy sequential np.add.at order, in f32
    float facc = 0.0f;
    int last = -1;
    for (;;) {
      int bestE = INT_MAX;
      for (int e = h; e >= 0; e = nxt[base + e])
        if (e > last && e < bestE) bestE = e;
      if (bestE == INT_MAX) break;
      facc = facc + eval[base + bestE];
      last = bestE;
    }
    term = pred[idx] * facc;                    // fl(pred * dflat)
  }
  __shared__ double red[256];
  red[threadIdx.x] = (double)term;
  __syncthreads();
  for (int s = 128; s > 0; s >>= 1) {
    if ((int)threadIdx.x < s) red[threadIdx.x] += red[threadIdx.x + s];
    __syncthreads();
  }
  if (threadIdx.x == 0 && red[0] != 0.0)
    atomicAdd(&acc[blockIdx.x * 256 / HW], red[0]);   // block never spans samples
}

__global__ void k_final(const double* __restrict__ acc, float* __restrict__ out) {
  if (threadIdx.x == 0 && blockIdx.x == 0) {
    double mi = (acc[0] + acc[1] + acc[2] + acc[3]) * 0.25;
    double mp = (acc[4] + acc[5] + acc[6] + acc[7]) * 0.25;
    out[0] = (float)(mi + mp);   // W_INJECT = W_PIXEL = 1
  }
}

extern "C" void kernel_launch(void* const* d_in, const int* in_sizes, int n_in,
                              void* d_out, int out_size, void* d_ws, size_t ws_size,
                              hipStream_t stream) {
  const float* pred = (const float*)d_in[0];
  const float* gt   = (const float*)d_in[1];
  float* out = (float*)d_out;
  char* ws = (char*)d_ws;

  double* acc        = (double*)(ws + OFF_ACC);
  int*    counts_raw = (int*)(ws + OFF_CNT);
  int*    wave_cnt   = (int*)(ws + OFF_WCNT);
  unsigned long long* masks = (unsigned long long*)(ws + OFF_MASKS);
  float2* pts        = (float2*)(ws + OFF_PTS);
  unsigned long long* part  = (unsigned long long*)(ws + OFF_PART);
  int*    heads      = (int*)(ws + OFF_HEADS);
  int*    nxt        = (int*)(ws + OFF_NXT);
  float*  eval       = (float*)(ws + OFF_EVAL);

  (void)in_sizes; (void)n_in; (void)out_size; (void)ws_size; // WS_NEED ~14.1 MB

  k_count<<<dim3(NFIELD * CBLK), dim3(256), 0, stream>>>(pred, gt, masks, wave_cnt,
                                                         heads, acc);
  k_emit<<<dim3(NFIELD * CBLK), dim3(256), 0, stream>>>(pred, gt, masks, wave_cnt,
                                                        pts, counts_raw);
  k_nn<<<dim3(B * 16 * GSPLIT), dim3(256), 0, stream>>>(pts, counts_raw, part);
  k_post<<<dim3(B * 16), dim3(256), 0, stream>>>(pred, pts, counts_raw, part,
                                                 heads, nxt, eval, acc);
  k_gather<<<dim3(B * HW / 256), dim3(256), 0, stream>>>(pred, heads, nxt, eval, acc);
  k_final<<<dim3(1), dim3(1), 0, stream>>>(acc, out);
}

// Round 4
// 89.949 us; speedup vs baseline: 3.9578x; 1.2507x over previous
//
#include <hip/hip_runtime.h>
#include <climits>

// ---------------------------------------------------------------------------
// ChamferBoundarySDFLoss — bitwise-f32 replication of the numpy reference.
// R4: row-aligned read-once ballot compaction (12-deep MLP), row-bbox skip
// in NN, dirty-block gather. 6 dispatches.
// ---------------------------------------------------------------------------

typedef unsigned long long ull;

constexpr int B = 4, H = 768, W = 768, K = 4096;
constexpr int HW = H * W;
constexpr int NFIELD = 2 * B;            // field f: sample f>>1, f&1: 0=pred 1=gt
constexpr int BANDS = 256;               // 3 rows per band
constexpr int WPR = W / 64;              // 12 mask words per row
constexpr int SEGW = 768 * WPR;          // words per segment (z/v/h, row-aligned)
constexpr int MSTRIDE = 3 * SEGW;        // words per field
constexpr int GSPLIT = 16;               // gt-range split for NN
constexpr int GRNG = K / GSPLIT;         // 256 gt pts per NN block
constexpr int NDBLK = B * HW / 256;      // 9216 gather blocks

// workspace layout (bytes)
constexpr size_t OFF_ACC   = 0;                                        // double[8]
constexpr size_t OFF_CNT   = OFF_ACC + sizeof(double) * 8;             // int[NFIELD]
constexpr size_t OFF_WCNT  = OFF_CNT + sizeof(int) * NFIELD;           // int[NFIELD*768]
constexpr size_t OFF_MASKS = (OFF_WCNT + sizeof(int) * NFIELD * 768 + 7) & ~size_t(7);
constexpr size_t OFF_PTS   = OFF_MASKS + sizeof(ull) * NFIELD * MSTRIDE;
constexpr size_t OFF_PART  = OFF_PTS + sizeof(float2) * NFIELD * K;    // ull[B*GSPLIT*K]
constexpr size_t OFF_HEADS = OFF_PART + sizeof(ull) * (size_t)B * GSPLIT * K;
constexpr size_t OFF_NXT   = OFF_HEADS + sizeof(int) * (size_t)B * HW;
constexpr size_t OFF_EVAL  = OFF_NXT + sizeof(int) * (size_t)B * 4 * K;
constexpr size_t OFF_DIRTY = OFF_EVAL + sizeof(float) * (size_t)B * 4 * K;
constexpr size_t WS_NEED   = OFF_DIRTY + sizeof(int) * NDBLK;          // ~14.2 MB

#define DEVFN __device__ __forceinline__

DEVFN float grad_r(const float* __restrict__ s, int r, int c) {
#pragma clang fp contract(off)
  if (r == 0)      return s[W + c] - s[c];
  if (r == H - 1)  return s[(H - 1) * W + c] - s[(H - 2) * W + c];
  return 0.5f * (s[(r + 1) * W + c] - s[(r - 1) * W + c]);
}
DEVFN float grad_c(const float* __restrict__ s, int r, int c) {
#pragma clang fp contract(off)
  if (c == 0)      return s[r * W + 1] - s[r * W];
  if (c == W - 1)  return s[r * W + W - 1] - s[r * W + W - 2];
  return 0.5f * (s[r * W + c + 1] - s[r * W + c - 1]);
}

DEVFN const float* field_sdf(const float* pred, const float* gt, int f) {
  return ((f & 1) ? gt : pred) + (size_t)(f >> 1) * HW;
}

// Row-aligned single-pass count: wave = (field, 3-row band). Reads each row
// once as 12 independent coalesced loads; z/v/h predicates from registers.
// Also clears heads/dirty/acc (used only by later kernels in-stream).
__global__ __launch_bounds__(256) void k_count(const float* __restrict__ pred,
                                               const float* __restrict__ gt,
                                               ull* __restrict__ masks,
                                               int* __restrict__ wave_cnt,
                                               int* __restrict__ heads,
                                               int* __restrict__ dirty,
                                               double* __restrict__ acc) {
#pragma clang fp contract(off)
  int gtid = blockIdx.x * 256 + (int)threadIdx.x;
  for (int idx = gtid; idx < B * HW; idx += gridDim.x * 256) heads[idx] = -1;
  for (int idx = gtid; idx < NDBLK; idx += gridDim.x * 256) dirty[idx] = 0;
  if (gtid < 8) acc[gtid] = 0.0;

  int f = blockIdx.x >> 6;                    // 64 blocks/field
  int bb = blockIdx.x & 63;
  int wave = threadIdx.x >> 6, lane = threadIdx.x & 63;
  int band = bb * 4 + wave;
  int r0 = band * 3;
  const float* sdf = field_sdf(pred, gt, f);
  ull* mz = masks + (size_t)f * MSTRIDE;
  ull* mv = mz + SEGW;
  ull* mh = mv + SEGW;

  float cur[WPR], nxt[WPR];
#pragma unroll
  for (int i = 0; i < WPR; ++i) cur[i] = sdf[r0 * W + i * 64 + lane];
  int cz = 0, cv = 0, ch = 0;
  for (int rr = 0; rr < 3; ++rr) {
    int row = r0 + rr;
    bool hasNext = row < H - 1;
    if (hasNext) {
#pragma unroll
      for (int i = 0; i < WPR; ++i) nxt[i] = sdf[(row + 1) * W + i * 64 + lane];
    }
#pragma unroll
    for (int i = 0; i < WPR; ++i) {
      ull m = __ballot(cur[i] == 0.0f);                       // z: sdf == 0
      if (lane == 0) mz[row * WPR + i] = m;
      cz += __popcll(m);
      float nb = __shfl_down(cur[i], 1);
      float nb2 = (i < WPR - 1) ? __shfl(cur[i + 1], 0) : 0.0f;
      if (lane == 63) nb = nb2;
      bool hp = (i * 64 + lane < W - 1) && (cur[i] * nb < 0.0f);  // h: s[c]*s[c+1]<0
      m = __ballot(hp);
      if (lane == 0) mh[row * WPR + i] = m;
      ch += __popcll(m);
      if (hasNext) {
        m = __ballot(cur[i] * nxt[i] < 0.0f);                 // v: s[r]*s[r+1]<0
        if (lane == 0) mv[row * WPR + i] = m;
        cv += __popcll(m);
      }
    }
    if (hasNext) {
#pragma unroll
      for (int i = 0; i < WPR; ++i) cur[i] = nxt[i];
    }
  }
  if (lane == 0) {
    int* wc = wave_cnt + f * 768;
    wc[0 * BANDS + band] = cz;
    wc[1 * BANDS + band] = cv;
    wc[2 * BANDS + band] = ch;
  }
}

// Ordered emit: wave = (field, seg, band); prefix over 768 per-task counts
// (enumeration order = z bands, v bands, h bands = ascending g). Bitwise
// alpha math identical to the reference.
__global__ __launch_bounds__(256) void k_emit(const float* __restrict__ pred,
                                              const float* __restrict__ gt,
                                              const ull* __restrict__ masks,
                                              const int* __restrict__ wave_cnt,
                                              float2* __restrict__ pts,
                                              int* __restrict__ counts_raw) {
#pragma clang fp contract(off)
  int f = blockIdx.x / 192;
  int tb = blockIdx.x - f * 192;
  __shared__ int cnt_s[768];
  for (int t = threadIdx.x; t < 768; t += 256) cnt_s[t] = wave_cnt[f * 768 + t];
  __syncthreads();
  int wave = threadIdx.x >> 6, lane = threadIdx.x & 63;
  int task = tb * 4 + wave;                  // 0..767
  int seg = task >> 8, band = task & 255;
  int a = 0;
  for (int idx = lane; idx < task; idx += 64) a += cnt_s[idx];
  for (int off = 32; off > 0; off >>= 1) a += __shfl_xor(a, off, 64);
  int base = a;
  if (tb == 0 && wave == 0) {
    int t2 = 0;
    for (int idx = lane; idx < 768; idx += 64) t2 += cnt_s[idx];
    for (int off = 32; off > 0; off >>= 1) t2 += __shfl_xor(t2, off, 64);
    if (lane == 0) counts_raw[f] = t2;
  }
  if (base >= K) return;
  const float* sdf = field_sdf(pred, gt, f);
  const ull* mseg = masks + (size_t)f * MSTRIDE + (size_t)seg * SEGW;
  float2* fp = pts + (size_t)f * K;
  int r0 = band * 3;
  for (int rr = 0; rr < 3; ++rr) {
    int row = r0 + rr;
    if (seg == 1 && row >= H - 1) break;     // v rows: 0..766
    for (int i = 0; i < WPR; ++i) {
      ull m = mseg[row * WPR + i];
      if (!m) continue;
      if ((m >> lane) & 1ull) {
        int c = i * 64 + lane;
        float pr, pc;
        if (seg == 0) {
          pr = (float)row; pc = (float)c;
        } else if (seg == 1) {
          float v1 = sdf[row * W + c], v2 = sdf[(row + 1) * W + c];
          float a1 = fabsf(v1), a2 = fabsf(v2);
          float alpha = a1 / ((a1 + a2) + 1e-8f);   // left-assoc, eps outside
          pr = (float)row + alpha; pc = (float)c;
        } else {
          float h1 = sdf[row * W + c], h2 = sdf[row * W + c + 1];
          float a1 = fabsf(h1), a2 = fabsf(h2);
          float alpha = a1 / ((a1 + a2) + 1e-8f);
          pr = (float)row; pc = (float)c + alpha;
        }
        int pos = base + __popcll(m & ((1ull << lane) - 1ull));
        if (pos < K) fp[pos] = make_float2(pr, pc);
      }
      base += __popcll(m);
      if (base >= K) { rr = 3; break; }      // later positions all >= K
    }
  }
}

// 1-NN over a gt sub-range: per-thread row-bbox skip (conservative vs the
// 9.0001 prune), then pruned exact path: d = sqrtf((dr*dr)+(dc*dc)),
// strict < = first-min. Partial keys written unconditionally.
__global__ __launch_bounds__(256) void k_nn(const float2* __restrict__ pts,
                                            const int* __restrict__ counts_raw,
                                            ull* __restrict__ part) {
#pragma clang fp contract(off)
  int b = blockIdx.x / (16 * GSPLIT);
  int rem = blockIdx.x - b * (16 * GSPLIT);
  int ib = rem / GSPLIT, ig = rem - ib * GSPLIT;
  int np_ = min(counts_raw[2 * b + 0], K);
  int ng  = min(counts_raw[2 * b + 1], K);
  int j0 = ig * GRNG, j1 = min(j0 + GRNG, ng);
  int n = j1 - j0;                           // may be <= 0
  const float2* gp = pts + (size_t)(2 * b + 1) * K;
  __shared__ float2 tile[GRNG];
  __shared__ float smin[256], smax[256];
  float rmin = __builtin_inff(), rmax = -__builtin_inff();
  for (int t = threadIdx.x; t < n; t += 256) {
    float2 g = gp[j0 + t];
    tile[t] = g;
    rmin = fminf(rmin, g.x);
    rmax = fmaxf(rmax, g.x);
  }
  smin[threadIdx.x] = rmin; smax[threadIdx.x] = rmax;
  __syncthreads();
  for (int s = 128; s > 0; s >>= 1) {
    if ((int)threadIdx.x < s) {
      smin[threadIdx.x] = fminf(smin[threadIdx.x], smin[threadIdx.x + s]);
      smax[threadIdx.x] = fmaxf(smax[threadIdx.x], smax[threadIdx.x + s]);
    }
    __syncthreads();
  }
  float gmin = smin[0] - 3.001f, gmax = smax[0] + 3.001f;

  int i = ib * 256 + (int)threadIdx.x;
  bool active = (i < np_);
  float best = __builtin_inff();
  unsigned bj = 0xffffffffu;
  if (active && n > 0) {
    float2 q = pts[(size_t)(2 * b) * K + i];
    float pr = q.x, pc = q.y;
    if (pr >= gmin && pr <= gmax) {          // row-sorted runs: usually skips
#pragma unroll 4
      for (int j = 0; j < n; ++j) {
        float dr = tile[j].x - pr;
        float dc = tile[j].y - pc;
        float sqf = fmaf(dr, dr, dc * dc);   // prune (slack 1e-5 >> fma delta)
        if (sqf <= 9.0001f) {
          float d = sqrtf((dr * dr) + (dc * dc));  // exact path
          if (d < best) { best = d; bj = (unsigned)(j0 + j); }
        }
      }
    }
  }
  ull key = active ? (((ull)__float_as_uint(best) << 32) | bj) : ~0ull;
  part[((size_t)b * GSPLIT + ig) * K + i] = key;
}

// pixel term + chamfer scatter; min-reduces GSPLIT partial keys; marks dirty
__global__ __launch_bounds__(256) void k_post(const float* __restrict__ pred,
                                              const float2* __restrict__ pts,
                                              const int* __restrict__ counts_raw,
                                              const ull* __restrict__ part,
                                              int* __restrict__ heads,
                                              int* __restrict__ nxt,
                                              float* __restrict__ eval,
                                              int* __restrict__ dirty,
                                              double* __restrict__ acc) {
#pragma clang fp contract(off)
  int b = blockIdx.x >> 4;
  int i = ((blockIdx.x & 15) << 8) + (int)threadIdx.x;
  const float* P = pred + (size_t)b * HW;
  int np_ = min(counts_raw[2 * b + 0], K);
  bool active = (i < np_);
  float sval = 0.0f;
  if (active) {
    ull key = ~0ull;                          // packed min: tie -> min j
    for (int s = 0; s < GSPLIT; ++s) {
      ull k2 = part[((size_t)b * GSPLIT + s) * K + i];
      key = k2 < key ? k2 : key;
    }
    float2 q = pts[(size_t)(2 * b) * K + i];
    float pr = q.x, pc = q.y;

    int r0 = (int)floorf(pr); r0 = r0 < 0 ? 0 : (r0 > H - 1 ? H - 1 : r0);
    int c0 = (int)floorf(pc); c0 = c0 < 0 ? 0 : (c0 > W - 1 ? W - 1 : c0);
    int r1 = (r0 + 1 > H - 1) ? H - 1 : r0 + 1;
    int c1 = (c0 + 1 > W - 1) ? W - 1 : c0 + 1;
    float ar = pr - (float)r0;
    float ac = pc - (float)c0;
    float omr = 1.0f - ar, omc = 1.0f - ac;
    float u00 = omr * omc, u01 = omr * ac, u10 = ar * omc, u11 = ar * ac;

    float v00 = P[r0 * W + c0], v01 = P[r0 * W + c1];
    float v10 = P[r1 * W + c0], v11 = P[r1 * W + c1];
    sval = (v00 * omr) * omc + (v01 * omr) * ac + (v10 * ar) * omc + (v11 * ar) * ac;

    float best = __uint_as_float((unsigned)(key >> 32));   // ~0 -> NaN -> false
    if (best <= 3.0f) {
      const float2* gp = pts + (size_t)(2 * b + 1) * K;
      float2 g = gp[(unsigned)(key & 0xffffffffu)];
      float grA = grad_r(P, r0, c0), grB = grad_r(P, r0, c1);
      float grC = grad_r(P, r1, c0), grD = grad_r(P, r1, c1);
      float gcA = grad_c(P, r0, c0), gcB = grad_c(P, r0, c1);
      float gcC = grad_c(P, r1, c0), gcD = grad_c(P, r1, c1);
      float n_r = ((grA * u00 + grB * u01) + grC * u10) + grD * u11;
      float n_c = ((gcA * u00 + gcB * u01) + gcC * u10) + gcD * u11;
      float nn = sqrtf((n_r * n_r) + (n_c * n_c));
      float den = nn + 1e-8f;
      float nrm_r = n_r / den, nrm_c = n_c / den;
      float dr = g.x - pr, dc = g.y - pc;                  // dir_vec = gt - pred
      float dot = (dr * nrm_r) + (dc * nrm_c);
      dot = dot * 1.0f;                                    // UPDATE_SCALE
      if (dot != 0.0f) {
        int px[4] = { r0 * W + c0, r0 * W + c1, r1 * W + c0, r1 * W + c1 };
        float cv[4] = { dot * u00, dot * u01, dot * u10, dot * u11 };
        int basee = b * 4 * K;
        for (int k2 = 0; k2 < 4; ++k2) {
          int e = k2 * K + i;                              // numpy add.at order id
          eval[basee + e] = cv[k2];
          nxt[basee + e] = atomicExch(&heads[(size_t)b * HW + px[k2]], e);
          dirty[(b * HW + px[k2]) >> 8] = 1;               // idempotent store
        }
      }
    }
  }
  __shared__ double red[256];
  red[threadIdx.x] = (double)sval;
  __syncthreads();
  for (int s = 128; s > 0; s >>= 1) {
    if ((int)threadIdx.x < s) red[threadIdx.x] += red[threadIdx.x + s];
    __syncthreads();
  }
  if (threadIdx.x == 0 && red[0] != 0.0) atomicAdd(&acc[4 + b], red[0]);
}

__global__ __launch_bounds__(256) void k_gather(const float* __restrict__ pred,
                                                const int* __restrict__ heads,
                                                const int* __restrict__ nxt,
                                                const float* __restrict__ eval,
                                                const int* __restrict__ dirty,
                                                double* __restrict__ acc) {
#pragma clang fp contract(off)
  if (!dirty[blockIdx.x]) return;            // broadcast load; ~78% of blocks
  int idx = blockIdx.x * 256 + (int)threadIdx.x;
  int b = idx / HW;
  float term = 0.0f;
  int h = heads[idx];
  if (h >= 0) {
    int base = b * 4 * K;
    float facc = 0.0f;                       // fold ascending id == np.add.at order
    int last = -1;
    for (;;) {
      int bestE = INT_MAX;
      for (int e = h; e >= 0; e = nxt[base + e])
        if (e > last && e < bestE) bestE = e;
      if (bestE == INT_MAX) break;
      facc = facc + eval[base + bestE];
      last = bestE;
    }
    term = pred[idx] * facc;                 // fl(pred * dflat)
  }
  __shared__ double red[256];
  red[threadIdx.x] = (double)term;
  __syncthreads();
  for (int s = 128; s > 0; s >>= 1) {
    if ((int)threadIdx.x < s) red[threadIdx.x] += red[threadIdx.x + s];
    __syncthreads();
  }
  if (threadIdx.x == 0 && red[0] != 0.0)
    atomicAdd(&acc[blockIdx.x * 256 / HW], red[0]);   // block never spans samples
}

__global__ void k_final(const double* __restrict__ acc, float* __restrict__ out) {
  if (threadIdx.x == 0 && blockIdx.x == 0) {
    double mi = (acc[0] + acc[1] + acc[2] + acc[3]) * 0.25;
    double mp = (acc[4] + acc[5] + acc[6] + acc[7]) * 0.25;
    out[0] = (float)(mi + mp);   // W_INJECT = W_PIXEL = 1
  }
}

extern "C" void kernel_launch(void* const* d_in, const int* in_sizes, int n_in,
                              void* d_out, int out_size, void* d_ws, size_t ws_size,
                              hipStream_t stream) {
  const float* pred = (const float*)d_in[0];
  const float* gt   = (const float*)d_in[1];
  float* out = (float*)d_out;
  char* ws = (char*)d_ws;

  double* acc        = (double*)(ws + OFF_ACC);
  int*    counts_raw = (int*)(ws + OFF_CNT);
  int*    wave_cnt   = (int*)(ws + OFF_WCNT);
  ull*    masks      = (ull*)(ws + OFF_MASKS);
  float2* pts        = (float2*)(ws + OFF_PTS);
  ull*    part       = (ull*)(ws + OFF_PART);
  int*    heads      = (int*)(ws + OFF_HEADS);
  int*    nxt        = (int*)(ws + OFF_NXT);
  float*  eval       = (float*)(ws + OFF_EVAL);
  int*    dirty      = (int*)(ws + OFF_DIRTY);

  (void)in_sizes; (void)n_in; (void)out_size; (void)ws_size; // WS_NEED ~14.2 MB

  k_count<<<dim3(NFIELD * 64), dim3(256), 0, stream>>>(pred, gt, masks, wave_cnt,
                                                       heads, dirty, acc);
  k_emit<<<dim3(NFIELD * 192), dim3(256), 0, stream>>>(pred, gt, masks, wave_cnt,
                                                       pts, counts_raw);
  k_nn<<<dim3(B * 16 * GSPLIT), dim3(256), 0, stream>>>(pts, counts_raw, part);
  k_post<<<dim3(B * 16), dim3(256), 0, stream>>>(pred, pts, counts_raw, part,
                                                 heads, nxt, eval, dirty, acc);
  k_gather<<<dim3(NDBLK), dim3(256), 0, stream>>>(pred, heads, nxt, eval, dirty, acc);
  k_final<<<dim3(1), dim3(1), 0, stream>>>(acc, out);
}